// Round 6
// baseline (79.312 us; speedup 1.0000x reference)
//
#include <hip/hip_runtime.h>

#define B_ 32
#define T_ 8192
#define D_ 128
#define MBLK 128
#define NCHUNK 64    // T_/MBLK
#define CPB 4        // chunks per block
#define GRID_MAIN (B_ * (NCHUNK / CPB))   // 512 = 2 blocks/CU, all resident

typedef __attribute__((ext_vector_type(8))) _Float16 half8;
typedef __attribute__((ext_vector_type(4))) float floatx4;

__device__ __forceinline__ float tanh_fast(float x) {
    float e = __expf(2.0f * x);
    return 1.0f - __fdividef(2.0f, e + 1.0f);
}

// K0 (fused prep): blocks 0-7 pack W1 MFMA B-fragments; blocks 8-23 compute bias.
// B[k][n]: lane l holds n = ni*16 + (l&15), k = kk*32 + (l>>4)*8 + j  (j=0..7).
__global__ void prep_kernel(const float* __restrict__ W1, half8* __restrict__ W1frag,
                            const float* __restrict__ dec, const float* __restrict__ W2,
                            float* __restrict__ bias) {
    int bid = blockIdx.x, tid = threadIdx.x;
    if (bid < 8) {
        int tg = bid * 256 + tid;   // (kk*8+ni)*64+lane
        int kk = tg >> 9, ni = (tg >> 6) & 7, lane = tg & 63;
        half8 h;
        #pragma unroll
        for (int j = 0; j < 8; ++j) {
            int k = kk * 32 + ((lane >> 4) * 8) + j;
            int n = ni * 16 + (lane & 15);
            h[j] = (_Float16)W1[k * 128 + n];
        }
        W1frag[tg] = h;
    } else {
        int b = (bid - 8) * 2 + (tid >> 7);
        int d = tid & 127;
        float acc = 0.f;
        for (int h = 0; h < 128; ++h)
            acc += dec[b * 128 + h] * W2[h * 128 + d];
        bias[b * 128 + d] = acc;
    }
}

// K2: chunk-looped f16 MFMA GEMM + tanh + V-dot + softmax stats + context partial.
// 512 threads = 8 waves; wave w owns rows [w*16, w*16+16) of each 128-row chunk.
// Register prefetch: next chunk's enc loads fly under current chunk's compute.
__global__ __launch_bounds__(512)
void main_kernel(const float* __restrict__ enc, const half8* __restrict__ W1frag,
                 const float* __restrict__ bias, const float* __restrict__ V,
                 float* __restrict__ out_w, float* __restrict__ m_part,
                 float* __restrict__ s_part, float* __restrict__ c_part)
{
    __shared__ __align__(16) half8 bfr[2048];       // 32 KB W1 fragments
    __shared__ __align__(16) float red[MBLK];       // raw logits
    __shared__ __align__(16) float c_red[8][128];   // 4 KB per-wave context partials

    const int tid = threadIdx.x;
    const int l = tid & 63;
    const int w = tid >> 6;
    const int g = l >> 4;            // k-group / col-group
    const int bid = blockIdx.x;
    const int b = bid >> 4;                 // 16 blocks per batch
    const int cbase = (bid & 15) * CPB;     // 4 contiguous chunks
    const int arow = w * 16 + (l & 15);

    const float* rowp = enc + ((long)b * T_ + (long)cbase * MBLK + arow) * D_ + g * 8;

    // stage W1 fragments cooperatively (32 KB, L2-hot) — once per block
    #pragma unroll
    for (int q = 0; q < 4; ++q)
        bfr[q * 512 + tid] = W1frag[q * 512 + tid];

    // bias / V (L2-hot), overlap with staging
    float bs[8], vv[8];
    #pragma unroll
    for (int ni = 0; ni < 8; ++ni) {
        int n = ni * 16 + (l & 15);
        bs[ni] = bias[b * 128 + n];
        vv[ni] = V[n];
    }

    // prefetch chunk 0: lane l -> row arow, k = kk*32 + g*8 + j (8 x float4)
    float4 nf[8];
    #pragma unroll
    for (int kk = 0; kk < 4; ++kk) {
        nf[kk * 2]     = *(const float4*)(rowp + kk * 32);
        nf[kk * 2 + 1] = *(const float4*)(rowp + kk * 32 + 4);
    }
    __syncthreads();   // bfr ready

    #pragma unroll 1
    for (int ci = 0; ci < CPB; ++ci) {
        const int chunk = cbase + ci;

        // consume prefetched f32 -> f16 A-fragments
        half8 afr[4];
        #pragma unroll
        for (int kk = 0; kk < 4; ++kk) {
            float4 f0 = nf[kk * 2], f1 = nf[kk * 2 + 1];
            half8 a;
            a[0] = (_Float16)f0.x; a[1] = (_Float16)f0.y;
            a[2] = (_Float16)f0.z; a[3] = (_Float16)f0.w;
            a[4] = (_Float16)f1.x; a[5] = (_Float16)f1.y;
            a[6] = (_Float16)f1.z; a[7] = (_Float16)f1.w;
            afr[kk] = a;
        }

        // issue next chunk's loads — they fly under MFMA + epilogue + context
        if (ci < CPB - 1) {
            rowp += MBLK * D_;
            #pragma unroll
            for (int kk = 0; kk < 4; ++kk) {
                nf[kk * 2]     = *(const float4*)(rowp + kk * 32);
                nf[kk * 2 + 1] = *(const float4*)(rowp + kk * 32 + 4);
            }
        }

        floatx4 acc[8];
        #pragma unroll
        for (int ni = 0; ni < 8; ++ni) acc[ni] = (floatx4)0.0f;

        #pragma unroll
        for (int kk = 0; kk < 4; ++kk)
            #pragma unroll
            for (int ni = 0; ni < 8; ++ni)
                acc[ni] = __builtin_amdgcn_mfma_f32_16x16x32_f16(
                              afr[kk], bfr[(kk * 8 + ni) * 64 + l], acc[ni], 0, 0, 0);

        // epilogue: logit = sum_n tanh(score + bias[n]) * V[n]
        // C layout: col = ni*16 + (l&15), row = g*4 + j2   [m89-verified]
        float p[4];
        #pragma unroll
        for (int j2 = 0; j2 < 4; ++j2) {
            float q = 0.f;
            #pragma unroll
            for (int ni = 0; ni < 8; ++ni)
                q += tanh_fast(acc[ni][j2] + bs[ni]) * vv[ni];
            #pragma unroll
            for (int mk = 1; mk < 16; mk <<= 1)
                q += __shfl_xor(q, mk);
            p[j2] = q;
        }
        if ((l & 15) == 0) {
            floatx4 v4 = {p[0], p[1], p[2], p[3]};
            *(floatx4*)(&red[w * 16 + g * 4]) = v4;
            *(floatx4*)(out_w + (long)b * T_ + chunk * MBLK + w * 16 + g * 4) = v4;
        }
        __syncthreads();   // A: red[] ready

        // chunk softmax stats — redundantly per wave (no extra barrier)
        float l0 = red[l], l1 = red[l + 64];
        float m = fmaxf(l0, l1);
        #pragma unroll
        for (int mk = 1; mk < 64; mk <<= 1) m = fmaxf(m, __shfl_xor(m, mk));
        {
            float s = __expf(l0 - m) + __expf(l1 - m);
            #pragma unroll
            for (int mk = 1; mk < 64; mk <<= 1) s += __shfl_xor(s, mk);
            if (tid == 0) {
                m_part[b * NCHUNK + chunk] = m;
                s_part[b * NCHUNK + chunk] = s;
            }
        }

        // context partial from registers: reduce over the 16 row-lanes
        {
            float wgt = __expf(red[arow] - m);
            #pragma unroll
            for (int kk = 0; kk < 4; ++kk) {
                float cc[8];
                #pragma unroll
                for (int j = 0; j < 8; ++j) {
                    cc[j] = wgt * (float)afr[kk][j];
                    #pragma unroll
                    for (int mk = 1; mk < 16; mk <<= 1)
                        cc[j] += __shfl_xor(cc[j], mk);
                }
                if ((l & 15) == 0) {
                    floatx4 v0 = {cc[0], cc[1], cc[2], cc[3]};
                    floatx4 v1 = {cc[4], cc[5], cc[6], cc[7]};
                    *(floatx4*)(&c_red[w][kk * 32 + g * 8]) = v0;
                    *(floatx4*)(&c_red[w][kk * 32 + g * 8 + 4]) = v1;
                }
            }
        }
        __syncthreads();   // B: c_red ready (also protects red[] WAR for next chunk)
        if (tid < 128) {
            float s = 0.f;
            #pragma unroll
            for (int ww = 0; ww < 8; ++ww) s += c_red[ww][tid];
            c_part[((long)b * NCHUNK + chunk) * 128 + tid] = s;
        }
        // c_red WAR vs next chunk is protected by next iteration's barrier A
    }
}

// K3: per batch — global (m, 1/s) + context vector (small, 32 blocks)
__global__ __launch_bounds__(256)
void reduce_kernel(const float* __restrict__ m_part, const float* __restrict__ s_part,
                   const float* __restrict__ c_part, float* __restrict__ ctx,
                   float* __restrict__ mg, float* __restrict__ sginv)
{
    __shared__ float sc[64];
    __shared__ float stats[2];
    int b = blockIdx.x, tid = threadIdx.x;

    if (tid < 64) {
        float m = m_part[b * 64 + tid];
        float m_g = m;
        #pragma unroll
        for (int mk = 1; mk < 64; mk <<= 1) m_g = fmaxf(m_g, __shfl_xor(m_g, mk));
        float e = __expf(m - m_g);
        float s = s_part[b * 64 + tid] * e;
        #pragma unroll
        for (int mk = 1; mk < 64; mk <<= 1) s += __shfl_xor(s, mk);
        sc[tid] = e;
        if (tid == 0) {
            float inv = __fdividef(1.0f, s);
            stats[0] = m_g; stats[1] = inv;
            mg[b] = m_g; sginv[b] = inv;
        }
    }
    __syncthreads();
    float inv = stats[1];

    if (tid < 128) {
        float acc = 0.f;
        for (int ch = 0; ch < 64; ++ch)
            acc += c_part[((long)b * 64 + ch) * 128 + tid] * sc[ch];
        ctx[b * 128 + tid] = acc * inv;
    }
}

// K4: logits (already in d_out) -> softmax weights (wide, 1024 blocks)
__global__ void finalize_kernel(float* __restrict__ out_w, const float* __restrict__ mg,
                                const float* __restrict__ sginv)
{
    int idx = blockIdx.x * 256 + threadIdx.x;
    int b = idx >> 13;   // T_=8192
    float lg = out_w[idx];
    out_w[idx] = __expf(lg - mg[b]) * sginv[b];
}

extern "C" void kernel_launch(void* const* d_in, const int* in_sizes, int n_in,
                              void* d_out, int out_size, void* d_ws, size_t ws_size,
                              hipStream_t stream)
{
    const float* enc = (const float*)d_in[0];
    const float* dec = (const float*)d_in[1];
    const float* W1  = (const float*)d_in[2];
    const float* W2  = (const float*)d_in[3];
    const float* V   = (const float*)d_in[4];

    float* ctx  = (float*)d_out;          // [B, 128]
    float* outw = ctx + B_ * D_;          // [B, T]

    float* ws     = (float*)d_ws;
    float* bias   = ws;                   // 4096
    float* m_part = bias + 4096;          // 2048
    float* s_part = m_part + 2048;        // 2048
    float* mg     = s_part + 2048;        // 32
    float* sginv  = mg + 32;              // 32
    float* c_part = sginv + 32;           // 2048*128 = 262144
    half8* W1frag = (half8*)(c_part + (long)B_ * NCHUNK * 128);  // 32 KB, 16B-aligned

    prep_kernel<<<24, 256, 0, stream>>>(W1, W1frag, dec, W2, bias);
    main_kernel<<<GRID_MAIN, 512, 0, stream>>>(enc, W1frag, bias, V, outw, m_part, s_part, c_part);
    reduce_kernel<<<B_, 256, 0, stream>>>(m_part, s_part, c_part, ctx, mg, sginv);
    finalize_kernel<<<(B_ * T_) / 256, 256, 0, stream>>>(outw, mg, sginv);
}

// Round 7
// 52.197 us; speedup vs baseline: 1.5195x; 1.5195x over previous
//
#include <hip/hip_runtime.h>

#define B_ 32
#define T_ 8192
#define D_ 128
#define MBLK 128
#define NCHUNK 64    // T_/MBLK

typedef __attribute__((ext_vector_type(8))) _Float16 half8;
typedef __attribute__((ext_vector_type(4))) _Float16 half4;
typedef __attribute__((ext_vector_type(4))) float floatx4;

__device__ __forceinline__ float tanh_fast(float x) {
    float e = __expf(2.0f * x);
    return 1.0f - __fdividef(2.0f, e + 1.0f);
}

// K0 (fused prep): blocks 0-7 pack W1 MFMA B-fragments; blocks 8-23 compute bias.
// B[k][n]: lane l holds n = ni*16 + (l&15), k = kk*32 + (l>>4)*8 + j  (j=0..7).
__global__ void prep_kernel(const float* __restrict__ W1, half8* __restrict__ W1frag,
                            const float* __restrict__ dec, const float* __restrict__ W2,
                            float* __restrict__ bias) {
    int bid = blockIdx.x, tid = threadIdx.x;
    if (bid < 8) {
        int tg = bid * 256 + tid;   // (kk*8+ni)*64+lane
        int kk = tg >> 9, ni = (tg >> 6) & 7, lane = tg & 63;
        half8 h;
        #pragma unroll
        for (int j = 0; j < 8; ++j) {
            int k = kk * 32 + ((lane >> 4) * 8) + j;
            int n = ni * 16 + (lane & 15);
            h[j] = (_Float16)W1[k * 128 + n];
        }
        W1frag[tg] = h;
    } else {
        int b = (bid - 8) * 2 + (tid >> 7);
        int d = tid & 127;
        float acc = 0.f;
        for (int h = 0; h < 128; ++h)
            acc += dec[b * 128 + h] * W2[h * 128 + d];
        bias[b * 128 + d] = acc;
    }
}

// K2: f16 MFMA GEMM + tanh + V-dot + chunk softmax stats + chunk context partial.
// 512 threads = 8 waves; wave w owns rows [w*16, w*16+16).
// LDS union: bfr (W1 frags) lives until the MFMA loop ends, then the same 32 KB
// holds the f16 enc tile (written from registers) for the context pass.
__global__ __launch_bounds__(512)
void main_kernel(const float* __restrict__ enc, const half8* __restrict__ W1frag,
                 const float* __restrict__ bias, const float* __restrict__ V,
                 float* __restrict__ out_w, float* __restrict__ m_part,
                 float* __restrict__ s_part, float* __restrict__ c_part)
{
    __shared__ __align__(16) char smem_u[32768];    // union: bfr | encl
    __shared__ __align__(16) float red[MBLK];       // raw logits
    __shared__ __align__(16) float c_red[16][128];  // 8 KB context partials

    half8* bfr = (half8*)smem_u;     // phase 1: 2048 W1 fragments
    char*  encl = smem_u;            // phase 2: [128][128] f16, XOR-swizzled

    const int tid = threadIdx.x;
    const int l = tid & 63;
    const int w = tid >> 6;
    const int g = l >> 4;            // k-group / col-group
    const int bid = blockIdx.x;
    const int b = bid >> 6;          // NCHUNK=64 chunks per batch
    const int chunk = bid & 63;
    const int arow = w * 16 + (l & 15);
    const float* rowp = enc + ((long)b * T_ + (long)chunk * MBLK + arow) * D_ + g * 8;

    // stage W1 fragments via async global->LDS (16B/lane, wave-uniform dest base)
    #pragma unroll
    for (int q = 0; q < 4; ++q)
        __builtin_amdgcn_global_load_lds(
            (const __attribute__((address_space(1))) void*)(W1frag + q * 512 + tid),
            (__attribute__((address_space(3))) void*)(bfr + q * 512 + (w << 6)),
            16, 0, 0);

    // A-fragments straight from global: lane l -> row arow, k = kk*32+g*8+j
    half8 afr[4];
    #pragma unroll
    for (int kk = 0; kk < 4; ++kk) {
        float4 f0 = *(const float4*)(rowp + kk * 32);
        float4 f1 = *(const float4*)(rowp + kk * 32 + 4);
        half8 a;
        a[0] = (_Float16)f0.x; a[1] = (_Float16)f0.y;
        a[2] = (_Float16)f0.z; a[3] = (_Float16)f0.w;
        a[4] = (_Float16)f1.x; a[5] = (_Float16)f1.y;
        a[6] = (_Float16)f1.z; a[7] = (_Float16)f1.w;
        afr[kk] = a;
    }

    // bias / V (L2-hot)
    float bs[8], vv[8];
    #pragma unroll
    for (int ni = 0; ni < 8; ++ni) {
        int n = ni * 16 + (l & 15);
        bs[ni] = bias[b * 128 + n];
        vv[ni] = V[n];
    }
    __syncthreads();   // A: bfr ready (drains vmcnt incl. global_load_lds)

    floatx4 acc[8];
    #pragma unroll
    for (int ni = 0; ni < 8; ++ni) acc[ni] = (floatx4)0.0f;

    #pragma unroll
    for (int kk = 0; kk < 4; ++kk)
        #pragma unroll
        for (int ni = 0; ni < 8; ++ni)
            acc[ni] = __builtin_amdgcn_mfma_f32_16x16x32_f16(
                          afr[kk], bfr[(kk * 8 + ni) * 64 + l], acc[ni], 0, 0, 0);

    __syncthreads();   // B: all bfr reads done -> smem_u reusable as encl

    // park enc rows (f16, swizzled: byte ^= (row&7)<<4) for the context pass
    {
        const int asw = (arow & 7) << 4;
        #pragma unroll
        for (int kk = 0; kk < 4; ++kk) {
            int byte = arow * 256 + (((kk * 64) + (g * 16)) ^ asw);
            *(half8*)(encl + byte) = afr[kk];
        }
    }

    // epilogue: logit = sum_n tanh(score + bias[n]) * V[n]
    // C layout: col = ni*16 + (l&15), row = g*4 + j2   [m89-verified]
    float p[4];
    #pragma unroll
    for (int j2 = 0; j2 < 4; ++j2) {
        float q = 0.f;
        #pragma unroll
        for (int ni = 0; ni < 8; ++ni)
            q += tanh_fast(acc[ni][j2] + bs[ni]) * vv[ni];
        #pragma unroll
        for (int mk = 1; mk < 16; mk <<= 1)
            q += __shfl_xor(q, mk);
        p[j2] = q;
    }
    if ((l & 15) == 0) {
        floatx4 v4 = {p[0], p[1], p[2], p[3]};
        *(floatx4*)(&red[w * 16 + g * 4]) = v4;
        *(floatx4*)(out_w + (long)b * T_ + chunk * MBLK + w * 16 + g * 4) = v4;
    }
    __syncthreads();   // C: red[] + encl ready

    // chunk softmax stats — redundantly per wave (no extra barrier)
    float l0 = red[l], l1 = red[l + 64];
    float m = fmaxf(l0, l1);
    #pragma unroll
    for (int mk = 1; mk < 64; mk <<= 1) m = fmaxf(m, __shfl_xor(m, mk));
    {
        float s = __expf(l0 - m) + __expf(l1 - m);
        #pragma unroll
        for (int mk = 1; mk < 64; mk <<= 1) s += __shfl_xor(s, mk);
        if (tid == 0) {
            m_part[b * NCHUNK + chunk] = m;
            s_part[b * NCHUNK + chunk] = s;
        }
    }

    // context partial from LDS: 16 row-groups x 8 rows; lane owns 4 cols
    {
        const int rg = tid >> 5, dg = tid & 31;
        floatx4 cc = (floatx4)0.0f;
        #pragma unroll
        for (int rr = 0; rr < 8; ++rr) {
            int r = rg * 8 + rr;
            float wgt = __expf(red[r] - m);
            half4 h = *(const half4*)(encl + (r * 256 + ((dg * 8) ^ ((r & 7) << 4))));
            #pragma unroll
            for (int i = 0; i < 4; ++i) cc[i] += wgt * (float)h[i];
        }
        *(floatx4*)(&c_red[rg][dg * 4]) = cc;
    }
    __syncthreads();   // D: c_red ready
    if (tid < 128) {
        float s = 0.f;
        #pragma unroll
        for (int gg = 0; gg < 16; ++gg) s += c_red[gg][tid];
        c_part[((long)b * NCHUNK + chunk) * 128 + tid] = s;
    }
}

// K3: per batch — global (m, 1/s) + context vector (small, 32 blocks)
__global__ __launch_bounds__(256)
void reduce_kernel(const float* __restrict__ m_part, const float* __restrict__ s_part,
                   const float* __restrict__ c_part, float* __restrict__ ctx,
                   float* __restrict__ mg, float* __restrict__ sginv)
{
    __shared__ float sc[64];
    __shared__ float stats[2];
    int b = blockIdx.x, tid = threadIdx.x;

    if (tid < 64) {
        float m = m_part[b * 64 + tid];
        float m_g = m;
        #pragma unroll
        for (int mk = 1; mk < 64; mk <<= 1) m_g = fmaxf(m_g, __shfl_xor(m_g, mk));
        float e = __expf(m - m_g);
        float s = s_part[b * 64 + tid] * e;
        #pragma unroll
        for (int mk = 1; mk < 64; mk <<= 1) s += __shfl_xor(s, mk);
        sc[tid] = e;
        if (tid == 0) {
            float inv = __fdividef(1.0f, s);
            stats[0] = m_g; stats[1] = inv;
            mg[b] = m_g; sginv[b] = inv;
        }
    }
    __syncthreads();
    float inv = stats[1];

    if (tid < 128) {
        float acc = 0.f;
        for (int ch = 0; ch < 64; ++ch)
            acc += c_part[((long)b * 64 + ch) * 128 + tid] * sc[ch];
        ctx[b * 128 + tid] = acc * inv;
    }
}

// K4: logits (already in d_out) -> softmax weights (wide, 1024 blocks)
__global__ void finalize_kernel(float* __restrict__ out_w, const float* __restrict__ mg,
                                const float* __restrict__ sginv)
{
    int idx = blockIdx.x * 256 + threadIdx.x;
    int b = idx >> 13;   // T_=8192
    float lg = out_w[idx];
    out_w[idx] = __expf(lg - mg[b]) * sginv[b];
}

extern "C" void kernel_launch(void* const* d_in, const int* in_sizes, int n_in,
                              void* d_out, int out_size, void* d_ws, size_t ws_size,
                              hipStream_t stream)
{
    const float* enc = (const float*)d_in[0];
    const float* dec = (const float*)d_in[1];
    const float* W1  = (const float*)d_in[2];
    const float* W2  = (const float*)d_in[3];
    const float* V   = (const float*)d_in[4];

    float* ctx  = (float*)d_out;          // [B, 128]
    float* outw = ctx + B_ * D_;          // [B, T]

    float* ws     = (float*)d_ws;
    float* bias   = ws;                   // 4096
    float* m_part = bias + 4096;          // 2048
    float* s_part = m_part + 2048;        // 2048
    float* mg     = s_part + 2048;        // 32
    float* sginv  = mg + 32;              // 32
    float* c_part = sginv + 32;           // 2048*128 = 262144
    half8* W1frag = (half8*)(c_part + (long)B_ * NCHUNK * 128);  // 32 KB, 16B-aligned

    prep_kernel<<<24, 256, 0, stream>>>(W1, W1frag, dec, W2, bias);
    main_kernel<<<B_ * NCHUNK, 512, 0, stream>>>(enc, W1frag, bias, V, outw, m_part, s_part, c_part);
    reduce_kernel<<<B_, 256, 0, stream>>>(m_part, s_part, c_part, ctx, mg, sginv);
    finalize_kernel<<<(B_ * T_) / 256, 256, 0, stream>>>(outw, mg, sginv);
}